// Round 1
// baseline (400.263 us; speedup 1.0000x reference)
//
#include <hip/hip_runtime.h>
#include <stdint.h>

// CovPool: B=32, N=16384, D=64 fp32 -> per-batch cov (64x64), triu (2080/batch),
// globally sorted 66560 fp32 outputs.
// Strategy: S = X^T X via bf16 MFMA (stream x once, HBM-bound ~21us floor),
// mean in fp32 alongside; finalize cov; bucket-sort by top-16 key bits + exact
// per-run bitonic cleanup.
//
// Workspace layout (zeroed region first, ~1.52 MB total; assumes ws_size >= 2MB):
//   S       [32*64*64 f32]   @ 0        (524288 B)
//   Msum    [32*64 f32]      @ 524288   (8192 B)
//   hist    [65536 u32]      @ 532480   (262144 B)
//   wl_cnt  [u32 + pad]      @ 794624   (64 B)      <- zero region ends at 794688
//   offsets [65536 u32]      @ 794688   (262144 B)
//   tri     [66560 f32]      @ 1056832  (266240 B)
//   wl      [33280 uint2]    @ 1323072  (266240 B)

#define BATCHES 32
#define NSAMP   16384
#define DIM     64
#define LAMBDA  0.01f
#define NTRI    2080            // 64*65/2
#define NOUT    (BATCHES * NTRI) // 66560

#define CHUNKS_PER_BATCH 16
#define SAMP_PER_BLOCK   (NSAMP / CHUNKS_PER_BATCH)  // 1024
#define SAMP_PER_WAVE    (SAMP_PER_BLOCK / 4)        // 256
#define LDS_ROW_BYTES    72                          // 36 bf16 slots/dim (32 used + pad)
#define LDS_WAVE_BYTES   (DIM * LDS_ROW_BYTES)       // 4608

typedef __attribute__((ext_vector_type(4))) float f32x4;
typedef __attribute__((ext_vector_type(8))) short s16x8;

__device__ __forceinline__ uint32_t f32_to_bf16(float f) {
    uint32_t u = __builtin_bit_cast(uint32_t, f);
    return (u + 0x7FFFu + ((u >> 16) & 1u)) >> 16;   // RNE, no NaN inputs expected
}

__device__ __forceinline__ uint32_t sort_key(float v) {
    uint32_t u = __builtin_bit_cast(uint32_t, v);
    return u ^ (uint32_t)(((int32_t)u >> 31) | 0x80000000u);  // monotonic fp32->u32
}

// ---------------- K1: S = X^T X (bf16 MFMA) + column sums --------------------
__global__ __launch_bounds__(256, 2) void cov_kernel(const float* __restrict__ x,
                                                     float* __restrict__ S,
                                                     float* __restrict__ Msum) {
    __shared__ char lds_all[4 * LDS_WAVE_BYTES];
    const int tid  = threadIdx.x;
    const int wave = tid >> 6;
    const int lane = tid & 63;
    const int b     = blockIdx.x / CHUNKS_PER_BATCH;
    const int chunk = blockIdx.x % CHUNKS_PER_BATCH;
    const int n_start = chunk * SAMP_PER_BLOCK + wave * SAMP_PER_WAVE;
    const float* xb = x + ((size_t)b * NSAMP + n_start) * DIM;

    char* lds = lds_all + wave * LDS_WAVE_BYTES;   // wave-private: no barriers needed

    const int l15  = lane & 15;
    const int quad = lane >> 4;
    char* frag_base = lds + l15 * LDS_ROW_BYTES + quad * 16;

    f32x4 acc[10];
#pragma unroll
    for (int t = 0; t < 10; ++t) acc[t] = (f32x4){0.f, 0.f, 0.f, 0.f};
    float sum = 0.f;

    for (int kc = 0; kc < SAMP_PER_WAVE / 32; ++kc) {
        const float* xs = xb + kc * 32 * DIM + lane;
        float v[32];
#pragma unroll
        for (int j = 0; j < 32; ++j) v[j] = xs[j * DIM];   // coalesced, 32 in flight
#pragma unroll
        for (int j = 0; j < 32; ++j) sum += v[j];

        uint32_t p[16];
#pragma unroll
        for (int j = 0; j < 16; ++j)
            p[j] = f32_to_bf16(v[2 * j]) | (f32_to_bf16(v[2 * j + 1]) << 16);

        // transpose-store: lane owns dim=lane, samples 0..31 of this chunk
        char* wrow = lds + lane * LDS_ROW_BYTES;
#pragma unroll
        for (int j = 0; j < 8; ++j)
            *(uint2*)(wrow + j * 8) = make_uint2(p[2 * j], p[2 * j + 1]);

        // fragment loads: frag[t] = lane holds x[s0+quad*8+j][16t+l15], j=0..7
        // serves as both A-operand (m=l15) and B-operand (n=l15)
        s16x8 frag[4];
#pragma unroll
        for (int t = 0; t < 4; ++t) {
            uint2 lo = *(uint2*)(frag_base + t * 16 * LDS_ROW_BYTES);
            uint2 hi = *(uint2*)(frag_base + t * 16 * LDS_ROW_BYTES + 8);
            uint4 u = make_uint4(lo.x, lo.y, hi.x, hi.y);
            frag[t] = __builtin_bit_cast(s16x8, u);
        }

        // upper-triangular tiles: (0,0)(0,1)(0,2)(0,3)(1,1)(1,2)(1,3)(2,2)(2,3)(3,3)
        acc[0] = __builtin_amdgcn_mfma_f32_16x16x32_bf16(frag[0], frag[0], acc[0], 0, 0, 0);
        acc[1] = __builtin_amdgcn_mfma_f32_16x16x32_bf16(frag[0], frag[1], acc[1], 0, 0, 0);
        acc[2] = __builtin_amdgcn_mfma_f32_16x16x32_bf16(frag[0], frag[2], acc[2], 0, 0, 0);
        acc[3] = __builtin_amdgcn_mfma_f32_16x16x32_bf16(frag[0], frag[3], acc[3], 0, 0, 0);
        acc[4] = __builtin_amdgcn_mfma_f32_16x16x32_bf16(frag[1], frag[1], acc[4], 0, 0, 0);
        acc[5] = __builtin_amdgcn_mfma_f32_16x16x32_bf16(frag[1], frag[2], acc[5], 0, 0, 0);
        acc[6] = __builtin_amdgcn_mfma_f32_16x16x32_bf16(frag[1], frag[3], acc[6], 0, 0, 0);
        acc[7] = __builtin_amdgcn_mfma_f32_16x16x32_bf16(frag[2], frag[2], acc[7], 0, 0, 0);
        acc[8] = __builtin_amdgcn_mfma_f32_16x16x32_bf16(frag[2], frag[3], acc[8], 0, 0, 0);
        acc[9] = __builtin_amdgcn_mfma_f32_16x16x32_bf16(frag[3], frag[3], acc[9], 0, 0, 0);
    }

    // epilogue: C/D layout col=lane&15, row=quad*4+reg (m89-verified)
    const int tmi[10] = {0, 0, 0, 0, 1, 1, 1, 2, 2, 3};
    const int tni[10] = {0, 1, 2, 3, 1, 2, 3, 2, 3, 3};
    float* Sb = S + b * DIM * DIM;
#pragma unroll
    for (int t = 0; t < 10; ++t) {
        int d0 = tmi[t] * 16 + quad * 4;
        int e  = tni[t] * 16 + l15;
#pragma unroll
        for (int r = 0; r < 4; ++r)
            atomicAdd(&Sb[(d0 + r) * DIM + e], acc[t][r]);
    }
    atomicAdd(&Msum[b * DIM + lane], sum);
}

// ---------------- K2: finalize cov, emit triu values + histogram -------------
__global__ void finalize_kernel(const float* __restrict__ S,
                                const float* __restrict__ Msum,
                                float* __restrict__ tri,
                                uint32_t* __restrict__ hist) {
    int t = blockIdx.x * blockDim.x + threadIdx.x;  // 32*4096
    int b = t >> 12, de = t & 4095, d = de >> 6, e = de & 63;
    if (d > e) return;
    float ssum = S[b * 4096 + d * 64 + e];
    float md = Msum[b * 64 + d], me = Msum[b * 64 + e];
    float v = (ssum - md * me * (1.0f / NSAMP)) * (1.0f / (NSAMP - 1));
    if (d == e) v += LAMBDA;
    int p = d * 64 - (d * (d + 1)) / 2 + e;  // row-major triu index (matches triu_indices)
    tri[b * NTRI + p] = v;
    atomicAdd(&hist[sort_key(v) >> 16], 1u);
}

// ---------------- K3: single-block exclusive scan + worklist -----------------
__global__ __launch_bounds__(1024) void scan_kernel(const uint32_t* __restrict__ hist,
                                                    uint32_t* __restrict__ offsets,
                                                    uint2* __restrict__ wl,
                                                    uint32_t* __restrict__ wl_count) {
    __shared__ uint32_t sbuf[1024];
    int tid = threadIdx.x;
    int base = tid * 64;
    uint32_t s = 0;
    for (int i = 0; i < 64; ++i) s += hist[base + i];
    uint32_t mysum = s;
    sbuf[tid] = s;
    __syncthreads();
    for (int off = 1; off < 1024; off <<= 1) {
        uint32_t v = (tid >= off) ? sbuf[tid - off] : 0u;
        __syncthreads();
        sbuf[tid] += v;
        __syncthreads();
    }
    uint32_t run = sbuf[tid] - mysum;  // exclusive prefix
    for (int i = 0; i < 64; ++i) {
        uint32_t c = hist[base + i];
        offsets[base + i] = run;
        if (c >= 2u) {
            uint32_t w = atomicAdd(wl_count, 1u);
            wl[w] = make_uint2(run, c);
        }
        run += c;
    }
}

// ---------------- K4: scatter into bucket positions --------------------------
__global__ void scatter_kernel(const float* __restrict__ tri,
                               uint32_t* __restrict__ offsets,
                               float* __restrict__ out) {
    int i = blockIdx.x * blockDim.x + threadIdx.x;
    if (i >= NOUT) return;
    float v = tri[i];
    uint32_t pos = atomicAdd(&offsets[sort_key(v) >> 16], 1u);
    out[pos] = v;
}

// ---------------- K5: exact in-place sort of multi-element runs --------------
#define SORT_CAP 8192
__global__ __launch_bounds__(256) void runsort_kernel(float* __restrict__ out,
                                                      const uint2* __restrict__ wl,
                                                      const uint32_t* __restrict__ wl_count) {
    __shared__ float buf[SORT_CAP];
    uint32_t nw = *wl_count;
    for (uint32_t w = blockIdx.x; w < nw; w += gridDim.x) {
        uint2 ent = wl[w];
        uint32_t start = ent.x, cnt = ent.y;
        if (cnt > SORT_CAP) continue;  // statistically impossible here (<0.78%-wide value band)
        uint32_t m = 1;
        while (m < cnt) m <<= 1;
        for (uint32_t i = threadIdx.x; i < m; i += blockDim.x)
            buf[i] = (i < cnt) ? out[start + i] : __builtin_inff();
        __syncthreads();
        for (uint32_t k = 2; k <= m; k <<= 1) {
            for (uint32_t j = k >> 1; j > 0; j >>= 1) {
                for (uint32_t i = threadIdx.x; i < m; i += blockDim.x) {
                    uint32_t ixj = i ^ j;
                    if (ixj > i) {
                        float a = buf[i], c = buf[ixj];
                        bool up = ((i & k) == 0u);
                        if ((a > c) == up) { buf[i] = c; buf[ixj] = a; }
                    }
                }
                __syncthreads();
            }
        }
        for (uint32_t i = threadIdx.x; i < cnt; i += blockDim.x)
            out[start + i] = buf[i];
        __syncthreads();
    }
}

extern "C" void kernel_launch(void* const* d_in, const int* in_sizes, int n_in,
                              void* d_out, int out_size, void* d_ws, size_t ws_size,
                              hipStream_t stream) {
    const float* x = (const float*)d_in[0];
    float* out = (float*)d_out;
    char* ws = (char*)d_ws;

    float*    S        = (float*)(ws);
    float*    Msum     = (float*)(ws + 524288);
    uint32_t* hist     = (uint32_t*)(ws + 532480);
    uint32_t* wl_count = (uint32_t*)(ws + 794624);
    uint32_t* offsets  = (uint32_t*)(ws + 794688);
    float*    tri      = (float*)(ws + 1056832);
    uint2*    wl       = (uint2*)(ws + 1323072);

    hipMemsetAsync(d_ws, 0, 794688, stream);  // zero S, Msum, hist, wl_count
    cov_kernel<<<BATCHES * CHUNKS_PER_BATCH, 256, 0, stream>>>(x, S, Msum);
    finalize_kernel<<<(BATCHES * 4096) / 256, 256, 0, stream>>>(S, Msum, tri, hist);
    scan_kernel<<<1, 1024, 0, stream>>>(hist, offsets, wl, wl_count);
    scatter_kernel<<<(NOUT + 255) / 256, 256, 0, stream>>>(tri, offsets, out);
    runsort_kernel<<<256, 256, 0, stream>>>(out, wl, wl_count);
}

// Round 2
// 366.210 us; speedup vs baseline: 1.0930x; 1.0930x over previous
//
#include <hip/hip_runtime.h>
#include <stdint.h>

// CovPool: B=32, N=16384, D=64 fp32 -> per-batch cov (64x64), triu, globally
// sorted 66560 fp32 outputs.
// R2: parallel 2-kernel scan (was 102us single-block), cov occupancy 8->16
// waves/CU + in-block reduction (atomics 5.2M->2.6M), split small/large run
// cleanup sorts.
//
// Workspace layout (zero region first = 794688 B):
//   S         [32*64*64 f32]  @ 0
//   Msum      [32*64 f32]     @ 524288
//   hist      [65536 u32]     @ 532480
//   counts    [2 u32 + pad]   @ 794624   <- zero region ends 794688
//   offsets   [65536 u32]     @ 794688
//   blocksums [256 u32]       @ 1056832
//   tri       [66560 f32]     @ 1057856
//   wl_small  [33280 uint2]   @ 1324096
//   wl_large  [1024 uint2]    @ 1590336  (ends 1598528)

#define BATCHES 32
#define NSAMP   16384
#define DIM     64
#define LAMBDA  0.01f
#define NTRI    2080
#define NOUT    (BATCHES * NTRI)   // 66560

#define CHUNKS_PER_BATCH 32
#define SAMP_PER_BLOCK   (NSAMP / CHUNKS_PER_BATCH)  // 512
#define SAMP_PER_WAVE    (SAMP_PER_BLOCK / 4)        // 128
#define LDS_ROW_BYTES    72
#define LDS_WAVE_BYTES   (DIM * LDS_ROW_BYTES)       // 4608

typedef __attribute__((ext_vector_type(4))) float f32x4;
typedef __attribute__((ext_vector_type(8))) short s16x8;

__device__ __forceinline__ uint32_t f32_to_bf16(float f) {
    uint32_t u = __builtin_bit_cast(uint32_t, f);
    return (u + 0x7FFFu + ((u >> 16) & 1u)) >> 16;   // RNE
}

__device__ __forceinline__ uint32_t sort_key(float v) {
    uint32_t u = __builtin_bit_cast(uint32_t, v);
    return u ^ (uint32_t)(((int32_t)u >> 31) | 0x80000000u);
}

// ---------------- K1: S = X^T X (bf16 MFMA) + column sums --------------------
__global__ __launch_bounds__(256, 4) void cov_kernel(const float* __restrict__ x,
                                                     float* __restrict__ S,
                                                     float* __restrict__ Msum) {
    __shared__ union {
        char  trans[4][LDS_WAVE_BYTES];   // 18432 B, used during K-loop
        float red[2][64][41];             // 20992 B, used in epilogue
    } lds_u;

    const int tid  = threadIdx.x;
    const int wave = tid >> 6;
    const int lane = tid & 63;
    const int b     = blockIdx.x / CHUNKS_PER_BATCH;
    const int chunk = blockIdx.x % CHUNKS_PER_BATCH;
    const int n_start = chunk * SAMP_PER_BLOCK + wave * SAMP_PER_WAVE;
    const float* xb = x + ((size_t)b * NSAMP + n_start) * DIM;

    char* lds = lds_u.trans[wave];  // wave-private during K-loop

    const int l15  = lane & 15;
    const int quad = lane >> 4;
    char* frag_base = lds + l15 * LDS_ROW_BYTES + quad * 16;
    char* wrow = lds + lane * LDS_ROW_BYTES;  // lane owns dim=lane

    f32x4 acc[10];
#pragma unroll
    for (int t = 0; t < 10; ++t) acc[t] = (f32x4){0.f, 0.f, 0.f, 0.f};
    float sum = 0.f;

    for (int kc = 0; kc < SAMP_PER_WAVE / 32; ++kc) {
#pragma unroll
        for (int h = 0; h < 2; ++h) {   // two 16-sample half-batches per 32-K chunk
            const float* xs = xb + (kc * 32 + h * 16) * DIM + lane;
            float v[16];
#pragma unroll
            for (int j = 0; j < 16; ++j) v[j] = xs[j * DIM];  // coalesced dword
#pragma unroll
            for (int j = 0; j < 16; ++j) sum += v[j];
            uint32_t p[8];
#pragma unroll
            for (int j = 0; j < 8; ++j)
                p[j] = f32_to_bf16(v[2 * j]) | (f32_to_bf16(v[2 * j + 1]) << 16);
#pragma unroll
            for (int j = 0; j < 4; ++j)
                *(uint2*)(wrow + h * 32 + j * 8) = make_uint2(p[2 * j], p[2 * j + 1]);
        }

        s16x8 frag[4];
#pragma unroll
        for (int t = 0; t < 4; ++t) {
            uint2 lo = *(uint2*)(frag_base + t * 16 * LDS_ROW_BYTES);
            uint2 hi = *(uint2*)(frag_base + t * 16 * LDS_ROW_BYTES + 8);
            uint4 u = make_uint4(lo.x, lo.y, hi.x, hi.y);
            frag[t] = __builtin_bit_cast(s16x8, u);
        }

        acc[0] = __builtin_amdgcn_mfma_f32_16x16x32_bf16(frag[0], frag[0], acc[0], 0, 0, 0);
        acc[1] = __builtin_amdgcn_mfma_f32_16x16x32_bf16(frag[0], frag[1], acc[1], 0, 0, 0);
        acc[2] = __builtin_amdgcn_mfma_f32_16x16x32_bf16(frag[0], frag[2], acc[2], 0, 0, 0);
        acc[3] = __builtin_amdgcn_mfma_f32_16x16x32_bf16(frag[0], frag[3], acc[3], 0, 0, 0);
        acc[4] = __builtin_amdgcn_mfma_f32_16x16x32_bf16(frag[1], frag[1], acc[4], 0, 0, 0);
        acc[5] = __builtin_amdgcn_mfma_f32_16x16x32_bf16(frag[1], frag[2], acc[5], 0, 0, 0);
        acc[6] = __builtin_amdgcn_mfma_f32_16x16x32_bf16(frag[1], frag[3], acc[6], 0, 0, 0);
        acc[7] = __builtin_amdgcn_mfma_f32_16x16x32_bf16(frag[2], frag[2], acc[7], 0, 0, 0);
        acc[8] = __builtin_amdgcn_mfma_f32_16x16x32_bf16(frag[2], frag[3], acc[8], 0, 0, 0);
        acc[9] = __builtin_amdgcn_mfma_f32_16x16x32_bf16(frag[3], frag[3], acc[9], 0, 0, 0);
    }

    // ---- in-block reduction of 4 waves' accumulators (atomics /4) ----
    __syncthreads();   // all waves done with trans region
    if (wave == 1 || wave == 3) {
        int slot = wave >> 1;
#pragma unroll
        for (int t = 0; t < 10; ++t)
#pragma unroll
            for (int r = 0; r < 4; ++r) lds_u.red[slot][lane][t * 4 + r] = acc[t][r];
    }
    __syncthreads();
    if (wave == 0 || wave == 2) {
        int slot = wave >> 1;
#pragma unroll
        for (int t = 0; t < 10; ++t)
#pragma unroll
            for (int r = 0; r < 4; ++r) acc[t][r] += lds_u.red[slot][lane][t * 4 + r];
    }
    __syncthreads();
    if (wave == 2) {
#pragma unroll
        for (int t = 0; t < 10; ++t)
#pragma unroll
            for (int r = 0; r < 4; ++r) lds_u.red[0][lane][t * 4 + r] = acc[t][r];
    }
    __syncthreads();

    atomicAdd(&Msum[b * DIM + lane], sum);

    if (wave == 0) {
#pragma unroll
        for (int t = 0; t < 10; ++t)
#pragma unroll
            for (int r = 0; r < 4; ++r) acc[t][r] += lds_u.red[0][lane][t * 4 + r];

        const int tmi[10] = {0, 0, 0, 0, 1, 1, 1, 2, 2, 3};
        const int tni[10] = {0, 1, 2, 3, 1, 2, 3, 2, 3, 3};
        float* Sb = S + b * DIM * DIM;
#pragma unroll
        for (int t = 0; t < 10; ++t) {
            int d0 = tmi[t] * 16 + quad * 4;
            int e  = tni[t] * 16 + l15;
#pragma unroll
            for (int r = 0; r < 4; ++r)
                atomicAdd(&Sb[(d0 + r) * DIM + e], acc[t][r]);
        }
    }
}

// ---------------- K2: finalize cov, emit triu values + histogram -------------
__global__ void finalize_kernel(const float* __restrict__ S,
                                const float* __restrict__ Msum,
                                float* __restrict__ tri,
                                uint32_t* __restrict__ hist) {
    int t = blockIdx.x * blockDim.x + threadIdx.x;
    int b = t >> 12, de = t & 4095, d = de >> 6, e = de & 63;
    if (d > e) return;
    float ssum = S[b * 4096 + d * 64 + e];
    float md = Msum[b * 64 + d], me = Msum[b * 64 + e];
    float v = (ssum - md * me * (1.0f / NSAMP)) * (1.0f / (NSAMP - 1));
    if (d == e) v += LAMBDA;
    int p = d * 64 - (d * (d + 1)) / 2 + e;
    tri[b * NTRI + p] = v;
    atomicAdd(&hist[sort_key(v) >> 16], 1u);
}

// ---------------- K3a: per-256-bucket partial sums ---------------------------
__global__ __launch_bounds__(256) void scanA_kernel(const uint32_t* __restrict__ hist,
                                                    uint32_t* __restrict__ blocksums) {
    __shared__ uint32_t s[256];
    int tid = threadIdx.x;
    s[tid] = hist[blockIdx.x * 256 + tid];
    __syncthreads();
    for (int off = 128; off > 0; off >>= 1) {
        if (tid < off) s[tid] += s[tid + off];
        __syncthreads();
    }
    if (tid == 0) blocksums[blockIdx.x] = s[0];
}

// ---------------- K3b: offsets + worklists -----------------------------------
__global__ __launch_bounds__(256) void scanB_kernel(const uint32_t* __restrict__ hist,
                                                    const uint32_t* __restrict__ blocksums,
                                                    uint32_t* __restrict__ offsets,
                                                    uint2* __restrict__ wl_small,
                                                    uint2* __restrict__ wl_large,
                                                    uint32_t* __restrict__ counts) {
    __shared__ uint32_t bs[256];
    __shared__ uint32_t sc[256];
    int tid = threadIdx.x, bid = blockIdx.x;

    bs[tid] = blocksums[tid];
    __syncthreads();
    for (int off = 1; off < 256; off <<= 1) {   // inclusive Hillis-Steele
        uint32_t a = (tid >= off) ? bs[tid - off] : 0u;
        __syncthreads();
        bs[tid] += a;
        __syncthreads();
    }
    uint32_t base = (bid > 0) ? bs[bid - 1] : 0u;

    uint32_t v = hist[bid * 256 + tid];
    sc[tid] = v;
    __syncthreads();
    for (int off = 1; off < 256; off <<= 1) {
        uint32_t a = (tid >= off) ? sc[tid - off] : 0u;
        __syncthreads();
        sc[tid] += a;
        __syncthreads();
    }
    uint32_t excl = base + sc[tid] - v;
    offsets[bid * 256 + tid] = excl;
    if (v >= 2u) {
        if (v <= 64u) {
            uint32_t w = atomicAdd(&counts[0], 1u);
            wl_small[w] = make_uint2(excl, v);
        } else {
            uint32_t w = atomicAdd(&counts[1], 1u);
            wl_large[w] = make_uint2(excl, v);
        }
    }
}

// ---------------- K4: scatter into bucket positions --------------------------
__global__ void scatter_kernel(const float* __restrict__ tri,
                               uint32_t* __restrict__ offsets,
                               float* __restrict__ out) {
    int i = blockIdx.x * blockDim.x + threadIdx.x;
    if (i >= NOUT) return;
    float v = tri[i];
    uint32_t pos = atomicAdd(&offsets[sort_key(v) >> 16], 1u);
    out[pos] = v;
}

// ---------------- K5a: wave-level shuffle bitonic for runs <= 64 -------------
__global__ __launch_bounds__(256) void runsort_small_kernel(float* __restrict__ out,
                                                            const uint2* __restrict__ wl,
                                                            const uint32_t* __restrict__ counts) {
    uint32_t nw = counts[0];
    int wave = threadIdx.x >> 6, lane = threadIdx.x & 63;
    for (uint32_t r = blockIdx.x * 4 + wave; r < nw; r += gridDim.x * 4) {
        uint2 e = wl[r];
        uint32_t start = e.x, cnt = e.y;
        float v = (lane < (int)cnt) ? out[start + lane] : __builtin_inff();
#pragma unroll
        for (uint32_t k = 2; k <= 64; k <<= 1)
            for (uint32_t j = k >> 1; j > 0; j >>= 1) {
                float p = __shfl_xor(v, (int)j, 64);
                bool keepmin = (((lane & k) == 0u) == ((lane & j) == 0u));
                v = keepmin ? fminf(v, p) : fmaxf(v, p);
            }
        if (lane < (int)cnt) out[start + lane] = v;
    }
}

// ---------------- K5b: LDS bitonic for runs 65..8192 -------------------------
#define SORT_CAP 8192
__global__ __launch_bounds__(256) void runsort_large_kernel(float* __restrict__ out,
                                                            const uint2* __restrict__ wl,
                                                            const uint32_t* __restrict__ counts) {
    __shared__ float buf[SORT_CAP];
    uint32_t nw = counts[1];
    for (uint32_t w = blockIdx.x; w < nw; w += gridDim.x) {
        uint2 ent = wl[w];
        uint32_t start = ent.x, cnt = ent.y;
        if (cnt > SORT_CAP) continue;
        uint32_t m = 1;
        while (m < cnt) m <<= 1;
        for (uint32_t i = threadIdx.x; i < m; i += blockDim.x)
            buf[i] = (i < cnt) ? out[start + i] : __builtin_inff();
        __syncthreads();
        for (uint32_t k = 2; k <= m; k <<= 1) {
            for (uint32_t j = k >> 1; j > 0; j >>= 1) {
                for (uint32_t i = threadIdx.x; i < m; i += blockDim.x) {
                    uint32_t ixj = i ^ j;
                    if (ixj > i) {
                        float a = buf[i], c = buf[ixj];
                        bool up = ((i & k) == 0u);
                        if ((a > c) == up) { buf[i] = c; buf[ixj] = a; }
                    }
                }
                __syncthreads();
            }
        }
        for (uint32_t i = threadIdx.x; i < cnt; i += blockDim.x)
            out[start + i] = buf[i];
        __syncthreads();
    }
}

extern "C" void kernel_launch(void* const* d_in, const int* in_sizes, int n_in,
                              void* d_out, int out_size, void* d_ws, size_t ws_size,
                              hipStream_t stream) {
    const float* x = (const float*)d_in[0];
    float* out = (float*)d_out;
    char* ws = (char*)d_ws;

    float*    S         = (float*)(ws);
    float*    Msum      = (float*)(ws + 524288);
    uint32_t* hist      = (uint32_t*)(ws + 532480);
    uint32_t* counts    = (uint32_t*)(ws + 794624);
    uint32_t* offsets   = (uint32_t*)(ws + 794688);
    uint32_t* blocksums = (uint32_t*)(ws + 1056832);
    float*    tri       = (float*)(ws + 1057856);
    uint2*    wl_small  = (uint2*)(ws + 1324096);
    uint2*    wl_large  = (uint2*)(ws + 1590336);

    hipMemsetAsync(d_ws, 0, 794688, stream);  // S, Msum, hist, counts
    cov_kernel<<<BATCHES * CHUNKS_PER_BATCH, 256, 0, stream>>>(x, S, Msum);
    finalize_kernel<<<(BATCHES * 4096) / 256, 256, 0, stream>>>(S, Msum, tri, hist);
    scanA_kernel<<<256, 256, 0, stream>>>(hist, blocksums);
    scanB_kernel<<<256, 256, 0, stream>>>(hist, blocksums, offsets, wl_small, wl_large, counts);
    scatter_kernel<<<260, 256, 0, stream>>>(tri, offsets, out);
    runsort_small_kernel<<<128, 256, 0, stream>>>(out, wl_small, counts);
    runsort_large_kernel<<<64, 256, 0, stream>>>(out, wl_large, counts);
}

// Round 3
// 330.780 us; speedup vs baseline: 1.2101x; 1.1071x over previous
//
#include <hip/hip_runtime.h>
#include <stdint.h>

// CovPool: B=32, N=16384, D=64 fp32 -> per-batch cov (64x64), triu, globally
// sorted 66560 fp32 outputs.
// R3: cov_kernel was atomic-RMW-bound (89 MB memory-side atomic writes).
// Replace global atomics with streamed per-block partials (10.7 MB) + fused
// reduce/finalize kernel. Atomic fallback path kept for small ws_size.
//
// Partial-path ws layout (zero region first = 262208 B):
//   hist      [65536 u32]       @ 0
//   counts    [16 u32]          @ 262144   <- zero region ends 262208
//   offsets   [65536 u32]       @ 262208
//   blocksums [256 u32]         @ 524352
//   tri       [66560 f32]       @ 525376
//   wl_small  [33280 uint2]     @ 791616
//   wl_large  [1024 uint2]      @ 1057856
//   partials  [1024][2624] f32  @ 1066048  (ends 11813952)

#define BATCHES 32
#define NSAMP   16384
#define DIM     64
#define LAMBDA  0.01f
#define NTRI    2080
#define NOUT    (BATCHES * NTRI)   // 66560

#define CHUNKS_PER_BATCH 32
#define SAMP_PER_BLOCK   (NSAMP / CHUNKS_PER_BATCH)  // 512
#define SAMP_PER_WAVE    (SAMP_PER_BLOCK / 4)        // 128
#define LDS_ROW_BYTES    72
#define LDS_WAVE_BYTES   (DIM * LDS_ROW_BYTES)       // 4608
#define PARTIAL_STRIDE   2624                        // 2560 S + 64 msum

typedef __attribute__((ext_vector_type(4))) float f32x4;
typedef __attribute__((ext_vector_type(8))) short s16x8;

__device__ __forceinline__ uint32_t f32_to_bf16(float f) {
    uint32_t u = __builtin_bit_cast(uint32_t, f);
    return (u + 0x7FFFu + ((u >> 16) & 1u)) >> 16;   // RNE
}

__device__ __forceinline__ uint32_t sort_key(float v) {
    uint32_t u = __builtin_bit_cast(uint32_t, v);
    return u ^ (uint32_t)(((int32_t)u >> 31) | 0x80000000u);
}

__constant__ const int c_tmi[10] = {0, 0, 0, 0, 1, 1, 1, 2, 2, 3};
__constant__ const int c_tni[10] = {0, 1, 2, 3, 1, 2, 3, 2, 3, 3};

// ============ shared device body: MFMA K-loop + in-block tree reduce =========
struct CovLds {
    union {
        char  trans[4][LDS_WAVE_BYTES];   // 18432 B (K-loop)
        float red[2][64][41];             // 20992 B (epilogue tree)
    } u;
    float msum_red[4][64];                // 1024 B
};

template <typename EpilogueFn>
__device__ __forceinline__ void cov_body(const float* __restrict__ x, CovLds& L,
                                         EpilogueFn epi) {
    const int tid  = threadIdx.x;
    const int wave = tid >> 6;
    const int lane = tid & 63;
    const int b     = blockIdx.x / CHUNKS_PER_BATCH;
    const int chunk = blockIdx.x % CHUNKS_PER_BATCH;
    const int n_start = chunk * SAMP_PER_BLOCK + wave * SAMP_PER_WAVE;
    const float* xb = x + ((size_t)b * NSAMP + n_start) * DIM;

    char* lds = L.u.trans[wave];  // wave-private during K-loop

    const int l15  = lane & 15;
    const int quad = lane >> 4;
    char* frag_base = lds + l15 * LDS_ROW_BYTES + quad * 16;
    char* wrow = lds + lane * LDS_ROW_BYTES;

    f32x4 acc[10];
#pragma unroll
    for (int t = 0; t < 10; ++t) acc[t] = (f32x4){0.f, 0.f, 0.f, 0.f};
    float sum = 0.f;

    for (int kc = 0; kc < SAMP_PER_WAVE / 32; ++kc) {
#pragma unroll
        for (int h = 0; h < 2; ++h) {
            const float* xs = xb + (kc * 32 + h * 16) * DIM + lane;
            float v[16];
#pragma unroll
            for (int j = 0; j < 16; ++j) v[j] = xs[j * DIM];  // coalesced dword
#pragma unroll
            for (int j = 0; j < 16; ++j) sum += v[j];
            uint32_t p[8];
#pragma unroll
            for (int j = 0; j < 8; ++j)
                p[j] = f32_to_bf16(v[2 * j]) | (f32_to_bf16(v[2 * j + 1]) << 16);
#pragma unroll
            for (int j = 0; j < 4; ++j)
                *(uint2*)(wrow + h * 32 + j * 8) = make_uint2(p[2 * j], p[2 * j + 1]);
        }

        s16x8 frag[4];
#pragma unroll
        for (int t = 0; t < 4; ++t) {
            uint2 lo = *(uint2*)(frag_base + t * 16 * LDS_ROW_BYTES);
            uint2 hi = *(uint2*)(frag_base + t * 16 * LDS_ROW_BYTES + 8);
            uint4 u = make_uint4(lo.x, lo.y, hi.x, hi.y);
            frag[t] = __builtin_bit_cast(s16x8, u);
        }

        acc[0] = __builtin_amdgcn_mfma_f32_16x16x32_bf16(frag[0], frag[0], acc[0], 0, 0, 0);
        acc[1] = __builtin_amdgcn_mfma_f32_16x16x32_bf16(frag[0], frag[1], acc[1], 0, 0, 0);
        acc[2] = __builtin_amdgcn_mfma_f32_16x16x32_bf16(frag[0], frag[2], acc[2], 0, 0, 0);
        acc[3] = __builtin_amdgcn_mfma_f32_16x16x32_bf16(frag[0], frag[3], acc[3], 0, 0, 0);
        acc[4] = __builtin_amdgcn_mfma_f32_16x16x32_bf16(frag[1], frag[1], acc[4], 0, 0, 0);
        acc[5] = __builtin_amdgcn_mfma_f32_16x16x32_bf16(frag[1], frag[2], acc[5], 0, 0, 0);
        acc[6] = __builtin_amdgcn_mfma_f32_16x16x32_bf16(frag[1], frag[3], acc[6], 0, 0, 0);
        acc[7] = __builtin_amdgcn_mfma_f32_16x16x32_bf16(frag[2], frag[2], acc[7], 0, 0, 0);
        acc[8] = __builtin_amdgcn_mfma_f32_16x16x32_bf16(frag[2], frag[3], acc[8], 0, 0, 0);
        acc[9] = __builtin_amdgcn_mfma_f32_16x16x32_bf16(frag[3], frag[3], acc[9], 0, 0, 0);
    }

    // ---- in-block tree reduction of 4 waves into wave0 ----
    L.msum_red[wave][lane] = sum;
    __syncthreads();   // also: all waves done with trans region
    if (wave == 1 || wave == 3) {
        int slot = wave >> 1;
#pragma unroll
        for (int t = 0; t < 10; ++t)
#pragma unroll
            for (int r = 0; r < 4; ++r) L.u.red[slot][lane][t * 4 + r] = acc[t][r];
    }
    __syncthreads();
    if (wave == 0 || wave == 2) {
        int slot = wave >> 1;
#pragma unroll
        for (int t = 0; t < 10; ++t)
#pragma unroll
            for (int r = 0; r < 4; ++r) acc[t][r] += L.u.red[slot][lane][t * 4 + r];
    }
    __syncthreads();
    if (wave == 2) {
#pragma unroll
        for (int t = 0; t < 10; ++t)
#pragma unroll
            for (int r = 0; r < 4; ++r) L.u.red[0][lane][t * 4 + r] = acc[t][r];
    }
    __syncthreads();
    if (wave == 0) {
#pragma unroll
        for (int t = 0; t < 10; ++t)
#pragma unroll
            for (int r = 0; r < 4; ++r) acc[t][r] += L.u.red[0][lane][t * 4 + r];
        float msum_tot = L.msum_red[0][lane] + L.msum_red[1][lane] +
                         L.msum_red[2][lane] + L.msum_red[3][lane];
        epi(b, lane, quad, l15, acc, msum_tot);
    }
}

// ---------------- K1p: partial-store variant (no atomics) --------------------
__global__ __launch_bounds__(256, 4) void cov_kernel_p(const float* __restrict__ x,
                                                       float* __restrict__ partials) {
    __shared__ CovLds L;
    float* Pb = partials + (size_t)blockIdx.x * PARTIAL_STRIDE;
    cov_body(x, L, [&](int b, int lane, int quad, int l15, f32x4* acc, float msum) {
#pragma unroll
        for (int t = 0; t < 10; ++t)
#pragma unroll
            for (int r = 0; r < 4; ++r)
                Pb[t * 256 + r * 64 + lane] = acc[t][r];   // coalesced stores
        Pb[2560 + lane] = msum;
    });
}

// ---------------- K1a: atomic fallback variant -------------------------------
__global__ __launch_bounds__(256, 4) void cov_kernel_a(const float* __restrict__ x,
                                                       float* __restrict__ S,
                                                       float* __restrict__ Msum) {
    __shared__ CovLds L;
    cov_body(x, L, [&](int b, int lane, int quad, int l15, f32x4* acc, float msum) {
        float* Sb = S + b * DIM * DIM;
#pragma unroll
        for (int t = 0; t < 10; ++t) {
            int d0 = c_tmi[t] * 16 + quad * 4;
            int e  = c_tni[t] * 16 + l15;
#pragma unroll
            for (int r = 0; r < 4; ++r)
                atomicAdd(&Sb[(d0 + r) * DIM + e], acc[t][r]);
        }
        atomicAdd(&Msum[b * DIM + lane], msum);
    });
}

// ---------------- K2p: reduce partials + finalize + histogram ----------------
__global__ __launch_bounds__(256) void reduce_kernel(const float* __restrict__ partials,
                                                     float* __restrict__ tri,
                                                     uint32_t* __restrict__ hist) {
    __shared__ float msum[DIM];
    const int b = blockIdx.x, tid = threadIdx.x;
    const float* P0 = partials + (size_t)b * CHUNKS_PER_BATCH * PARTIAL_STRIDE;

    float acc10[10];
#pragma unroll
    for (int k = 0; k < 10; ++k) acc10[k] = 0.f;
    float ms = 0.f;
    for (int c = 0; c < CHUNKS_PER_BATCH; ++c) {
        const float* P = P0 + c * PARTIAL_STRIDE;
#pragma unroll
        for (int k = 0; k < 10; ++k) acc10[k] += P[tid + 256 * k];  // coalesced
        if (tid < DIM) ms += P[2560 + tid];
    }
    if (tid < DIM) msum[tid] = ms;
    __syncthreads();

    const int r = tid >> 6, lane = tid & 63, quad = lane >> 4, l15 = lane & 15;
#pragma unroll
    for (int k = 0; k < 10; ++k) {
        int row = c_tmi[k] * 16 + quad * 4 + r;
        int col = c_tni[k] * 16 + l15;
        if (row <= col) {
            float v = (acc10[k] - msum[row] * msum[col] * (1.0f / NSAMP)) * (1.0f / (NSAMP - 1));
            if (row == col) v += LAMBDA;
            int p = row * 64 - (row * (row + 1)) / 2 + col;
            tri[b * NTRI + p] = v;
            atomicAdd(&hist[sort_key(v) >> 16], 1u);
        }
    }
}

// ---------------- K2a: finalize (atomic fallback path) -----------------------
__global__ void finalize_kernel(const float* __restrict__ S,
                                const float* __restrict__ Msum,
                                float* __restrict__ tri,
                                uint32_t* __restrict__ hist) {
    int t = blockIdx.x * blockDim.x + threadIdx.x;
    int b = t >> 12, de = t & 4095, d = de >> 6, e = de & 63;
    if (d > e) return;
    float ssum = S[b * 4096 + d * 64 + e];
    float md = Msum[b * 64 + d], me = Msum[b * 64 + e];
    float v = (ssum - md * me * (1.0f / NSAMP)) * (1.0f / (NSAMP - 1));
    if (d == e) v += LAMBDA;
    int p = d * 64 - (d * (d + 1)) / 2 + e;
    tri[b * NTRI + p] = v;
    atomicAdd(&hist[sort_key(v) >> 16], 1u);
}

// ---------------- K3a: per-256-bucket partial sums ---------------------------
__global__ __launch_bounds__(256) void scanA_kernel(const uint32_t* __restrict__ hist,
                                                    uint32_t* __restrict__ blocksums) {
    __shared__ uint32_t s[256];
    int tid = threadIdx.x;
    s[tid] = hist[blockIdx.x * 256 + tid];
    __syncthreads();
    for (int off = 128; off > 0; off >>= 1) {
        if (tid < off) s[tid] += s[tid + off];
        __syncthreads();
    }
    if (tid == 0) blocksums[blockIdx.x] = s[0];
}

// ---------------- K3b: offsets + worklists -----------------------------------
__global__ __launch_bounds__(256) void scanB_kernel(const uint32_t* __restrict__ hist,
                                                    const uint32_t* __restrict__ blocksums,
                                                    uint32_t* __restrict__ offsets,
                                                    uint2* __restrict__ wl_small,
                                                    uint2* __restrict__ wl_large,
                                                    uint32_t* __restrict__ counts) {
    __shared__ uint32_t bs[256];
    __shared__ uint32_t sc[256];
    int tid = threadIdx.x, bid = blockIdx.x;

    bs[tid] = blocksums[tid];
    __syncthreads();
    for (int off = 1; off < 256; off <<= 1) {
        uint32_t a = (tid >= off) ? bs[tid - off] : 0u;
        __syncthreads();
        bs[tid] += a;
        __syncthreads();
    }
    uint32_t base = (bid > 0) ? bs[bid - 1] : 0u;

    uint32_t v = hist[bid * 256 + tid];
    sc[tid] = v;
    __syncthreads();
    for (int off = 1; off < 256; off <<= 1) {
        uint32_t a = (tid >= off) ? sc[tid - off] : 0u;
        __syncthreads();
        sc[tid] += a;
        __syncthreads();
    }
    uint32_t excl = base + sc[tid] - v;
    offsets[bid * 256 + tid] = excl;
    if (v >= 2u) {
        if (v <= 64u) {
            uint32_t w = atomicAdd(&counts[0], 1u);
            wl_small[w] = make_uint2(excl, v);
        } else {
            uint32_t w = atomicAdd(&counts[1], 1u);
            wl_large[w] = make_uint2(excl, v);
        }
    }
}

// ---------------- K4: scatter into bucket positions --------------------------
__global__ void scatter_kernel(const float* __restrict__ tri,
                               uint32_t* __restrict__ offsets,
                               float* __restrict__ out) {
    int i = blockIdx.x * blockDim.x + threadIdx.x;
    if (i >= NOUT) return;
    float v = tri[i];
    uint32_t pos = atomicAdd(&offsets[sort_key(v) >> 16], 1u);
    out[pos] = v;
}

// ---------------- K5a: wave-level shuffle bitonic for runs <= 64 -------------
__global__ __launch_bounds__(256) void runsort_small_kernel(float* __restrict__ out,
                                                            const uint2* __restrict__ wl,
                                                            const uint32_t* __restrict__ counts) {
    uint32_t nw = counts[0];
    int wave = threadIdx.x >> 6, lane = threadIdx.x & 63;
    for (uint32_t r = blockIdx.x * 4 + wave; r < nw; r += gridDim.x * 4) {
        uint2 e = wl[r];
        uint32_t start = e.x, cnt = e.y;
        float v = (lane < (int)cnt) ? out[start + lane] : __builtin_inff();
#pragma unroll
        for (uint32_t k = 2; k <= 64; k <<= 1)
            for (uint32_t j = k >> 1; j > 0; j >>= 1) {
                float p = __shfl_xor(v, (int)j, 64);
                bool keepmin = (((lane & k) == 0u) == ((lane & j) == 0u));
                v = keepmin ? fminf(v, p) : fmaxf(v, p);
            }
        if (lane < (int)cnt) out[start + lane] = v;
    }
}

// ---------------- K5b: LDS bitonic for runs 65..8192 -------------------------
#define SORT_CAP 8192
__global__ __launch_bounds__(256) void runsort_large_kernel(float* __restrict__ out,
                                                            const uint2* __restrict__ wl,
                                                            const uint32_t* __restrict__ counts) {
    __shared__ float buf[SORT_CAP];
    uint32_t nw = counts[1];
    for (uint32_t w = blockIdx.x; w < nw; w += gridDim.x) {
        uint2 ent = wl[w];
        uint32_t start = ent.x, cnt = ent.y;
        if (cnt > SORT_CAP) continue;
        uint32_t m = 1;
        while (m < cnt) m <<= 1;
        for (uint32_t i = threadIdx.x; i < m; i += blockDim.x)
            buf[i] = (i < cnt) ? out[start + i] : __builtin_inff();
        __syncthreads();
        for (uint32_t k = 2; k <= m; k <<= 1) {
            for (uint32_t j = k >> 1; j > 0; j >>= 1) {
                for (uint32_t i = threadIdx.x; i < m; i += blockDim.x) {
                    uint32_t ixj = i ^ j;
                    if (ixj > i) {
                        float a = buf[i], c = buf[ixj];
                        bool up = ((i & k) == 0u);
                        if ((a > c) == up) { buf[i] = c; buf[ixj] = a; }
                    }
                }
                __syncthreads();
            }
        }
        for (uint32_t i = threadIdx.x; i < cnt; i += blockDim.x)
            out[start + i] = buf[i];
        __syncthreads();
    }
}

extern "C" void kernel_launch(void* const* d_in, const int* in_sizes, int n_in,
                              void* d_out, int out_size, void* d_ws, size_t ws_size,
                              hipStream_t stream) {
    const float* x = (const float*)d_in[0];
    float* out = (float*)d_out;
    char* ws = (char*)d_ws;

    const size_t NEED_P = 1066048 + (size_t)1024 * PARTIAL_STRIDE * 4;  // 11.8 MB

    if (ws_size >= NEED_P) {
        // ---- partial-store path (no global atomics in hot kernel) ----
        uint32_t* hist      = (uint32_t*)(ws);
        uint32_t* counts    = (uint32_t*)(ws + 262144);
        uint32_t* offsets   = (uint32_t*)(ws + 262208);
        uint32_t* blocksums = (uint32_t*)(ws + 524352);
        float*    tri       = (float*)(ws + 525376);
        uint2*    wl_small  = (uint2*)(ws + 791616);
        uint2*    wl_large  = (uint2*)(ws + 1057856);
        float*    partials  = (float*)(ws + 1066048);

        hipMemsetAsync(d_ws, 0, 262208, stream);  // hist + counts
        cov_kernel_p<<<BATCHES * CHUNKS_PER_BATCH, 256, 0, stream>>>(x, partials);
        reduce_kernel<<<BATCHES, 256, 0, stream>>>(partials, tri, hist);
        scanA_kernel<<<256, 256, 0, stream>>>(hist, blocksums);
        scanB_kernel<<<256, 256, 0, stream>>>(hist, blocksums, offsets, wl_small, wl_large, counts);
        scatter_kernel<<<260, 256, 0, stream>>>(tri, offsets, out);
        runsort_small_kernel<<<128, 256, 0, stream>>>(out, wl_small, counts);
        runsort_large_kernel<<<64, 256, 0, stream>>>(out, wl_large, counts);
    } else {
        // ---- atomic fallback path (round-2 layout) ----
        float*    S         = (float*)(ws);
        float*    Msum      = (float*)(ws + 524288);
        uint32_t* hist      = (uint32_t*)(ws + 532480);
        uint32_t* counts    = (uint32_t*)(ws + 794624);
        uint32_t* offsets   = (uint32_t*)(ws + 794688);
        uint32_t* blocksums = (uint32_t*)(ws + 1056832);
        float*    tri       = (float*)(ws + 1057856);
        uint2*    wl_small  = (uint2*)(ws + 1324096);
        uint2*    wl_large  = (uint2*)(ws + 1590336);

        hipMemsetAsync(d_ws, 0, 794688, stream);
        cov_kernel_a<<<BATCHES * CHUNKS_PER_BATCH, 256, 0, stream>>>(x, S, Msum);
        finalize_kernel<<<(BATCHES * 4096) / 256, 256, 0, stream>>>(S, Msum, tri, hist);
        scanA_kernel<<<256, 256, 0, stream>>>(hist, blocksums);
        scanB_kernel<<<256, 256, 0, stream>>>(hist, blocksums, offsets, wl_small, wl_large, counts);
        scatter_kernel<<<260, 256, 0, stream>>>(tri, offsets, out);
        runsort_small_kernel<<<128, 256, 0, stream>>>(out, wl_small, counts);
        runsort_large_kernel<<<64, 256, 0, stream>>>(out, wl_large, counts);
    }
}